// Round 1
// 203.969 us; speedup vs baseline: 1.0192x; 1.0192x over previous
//
#include <hip/hip_runtime.h>

// LinearConv2D: y[b, o=g*8+n, fi, t] =
//   sum_{d<8, fr<2, w<16} x[b, g*8+d, 2*fi+fr, 4*t+w] * wt[g*8+n, d, 2*fi+fr, w]
// Shapes: x[16,64,128,256] f32, wt[64,8,128,16] f32, out[16,64,64,61] f32.
//
// R8: weights off the scalar pipe. R4->R7 plateau at ~208us regardless of
// waves/CU and per-CU weight footprint => the 512 per-wave SMEM drains pay
// L2-class latency (sK$ shared per-SQC thrashes on 2 CUs x 16KB of distinct
// slices) and are neither TLP-hideable nor cacheable-away. Fix: stage the
// block's 8KB weight slice in LDS once, then uniform-address ds_read_b128
// broadcasts (in-order, ~120cy, hidden by a 2-deep n-pipeline under 128cy of
// FMAs per n). LDS port cost ~4k b128/CU x ~12cy ~= 20us, parallel to VALU.
// (R6's "LDS dead end" was b32-granularity: 16k reads/CU. float4 => 4x fewer.)
//  - LDS quad layout: q = n*64 + it*4 + qq  (it = d*2+fr) -> per-iter base
//    it*4, per-n stride 64 quads; all reads lane-uniform => broadcast.
//  - x register double-buffer per b unchanged (4 float4 x 4 b cur + prefetch).
//  - __launch_bounds__(256,2): ~210 VGPRs demanded, cap 256 -> NO spill
//    (spill tripwire: WRITE_SIZE must stay ~17MB).

namespace {
constexpr int kB  = 16;
constexpr int kC  = 64;
constexpr int kF  = 128;
constexpr int kT  = 256;
constexpr int kG  = 8;
constexpr int kD  = 8;
constexpr int kN  = 8;
constexpr int kW  = 16;
constexpr int kKS = 4;
constexpr int kNT = 61;   // (256-16)/4 + 1
constexpr int kO  = 64;
constexpr int kFP = 64;   // (128-2)/2 + 1
constexpr int kWStride = kD * kF * kW;  // 16384: per-n weight stride (floats)
}

__global__ __launch_bounds__(256, 2)
void lc2d_kernel(const float* __restrict__ x,
                 const float* __restrict__ wt,
                 float* __restrict__ out) {
  // Weight slice for this (g,fi): 8n x 8d x 2fr x 16w = 2048 f32 = 8 KB.
  __shared__ float4 wlds[512];

  const int tid  = threadIdx.x;
  const int lane = tid & 63;     // t
  const int wq   = tid >> 6;     // b-quad id
  const int fi   = blockIdx.x;   // 0..63
  const int g    = blockIdx.y;   // 0..7

  // ---- Stage weights -> LDS (one-time, coalesced in 128B runs of 8 thr) ----
  {
    const float* wb = wt + ((size_t)(g * kN) * kD * kF + (size_t)fi * 2) * kW;
#pragma unroll
    for (int r = 0; r < 2; ++r) {
      const int q  = tid + r * 256;      // 0..511
      const int n  = q >> 6;             // 0..7
      const int dd = (q >> 3) & 7;       // 0..7
      const int fr = (q >> 2) & 1;       // 0..1
      const int qq = q & 3;              // 0..3
      const float* src =
          wb + (size_t)n * kWStride + dd * (kF * kW) + fr * kW + qq * 4;
      wlds[q] = *(const float4*)src;
    }
  }

  // Clamp inactive lanes so their (dead) loads stay in-bounds.
  const int tc   = (lane < kNT - 1) ? lane : (kNT - 1);
  const int tau0 = tc * kKS;             // max 240; +15 = 255 in bounds

  const float* xb[4];
#pragma unroll
  for (int bb = 0; bb < 4; ++bb) {
    const int b = wq * 4 + bb;
    xb[bb] = x + (((size_t)b * kC + g * kD) * kF + fi * 2) * kT + tau0;
  }

  float acc[4][kN];
#pragma unroll
  for (int bb = 0; bb < 4; ++bb)
#pragma unroll
    for (int n = 0; n < kN; ++n) acc[bb][n] = 0.f;

  // Prime the x register double-buffer with row 0 (d=0, fr=0); overlaps with
  // the weight staging above.
  float4 cur[4][4];
#pragma unroll
  for (int bb = 0; bb < 4; ++bb)
#pragma unroll
    for (int q = 0; q < 4; ++q) cur[bb][q] = ((const float4*)xb[bb])[q];

  __syncthreads();   // weights visible before first wlds read

#pragma unroll 2
  for (int it = 0; it < 16; ++it) {
    // Prefetch next x row for all 4 b (it==15 reloads row 15 — L1 hit).
    const int nx = (it < 15) ? it + 1 : 15;
    const size_t roff = ((size_t)(nx >> 1) * kF + (nx & 1)) * kT;
    float4 pre[4][4];
#pragma unroll
    for (int bb = 0; bb < 4; ++bb) {
      const float* xr = xb[bb] + roff;
#pragma unroll
      for (int q = 0; q < 4; ++q) pre[bb][q] = ((const float4*)xr)[q];
    }

    // Weight quads for (d=it>>1, fr=it&1) live at wlds[it*4 + n*64 + qq].
    const int qb = it * 4;
    // n-pipeline: read n+1's quads while FMAing n's (ds latency ~120cy vs
    // 128cy of FMA issue per n).
    float4 w0 = wlds[qb + 0];
    float4 w1 = wlds[qb + 1];
    float4 w2 = wlds[qb + 2];
    float4 w3 = wlds[qb + 3];
#pragma unroll
    for (int n = 0; n < kN; ++n) {
      float4 nw0, nw1, nw2, nw3;
      if (n < kN - 1) {
        const int qn = qb + (n + 1) * 64;
        nw0 = wlds[qn + 0];
        nw1 = wlds[qn + 1];
        nw2 = wlds[qn + 2];
        nw3 = wlds[qn + 3];
      }
#pragma unroll
      for (int bb = 0; bb < 4; ++bb) {
        float a = acc[bb][n];
        a = fmaf(cur[bb][0].x, w0.x, a);
        a = fmaf(cur[bb][0].y, w0.y, a);
        a = fmaf(cur[bb][0].z, w0.z, a);
        a = fmaf(cur[bb][0].w, w0.w, a);
        a = fmaf(cur[bb][1].x, w1.x, a);
        a = fmaf(cur[bb][1].y, w1.y, a);
        a = fmaf(cur[bb][1].z, w1.z, a);
        a = fmaf(cur[bb][1].w, w1.w, a);
        a = fmaf(cur[bb][2].x, w2.x, a);
        a = fmaf(cur[bb][2].y, w2.y, a);
        a = fmaf(cur[bb][2].z, w2.z, a);
        a = fmaf(cur[bb][2].w, w2.w, a);
        a = fmaf(cur[bb][3].x, w3.x, a);
        a = fmaf(cur[bb][3].y, w3.y, a);
        a = fmaf(cur[bb][3].z, w3.z, a);
        a = fmaf(cur[bb][3].w, w3.w, a);
        acc[bb][n] = a;
      }
      if (n < kN - 1) {
        w0 = nw0; w1 = nw1; w2 = nw2; w3 = nw3;
      }
    }

#pragma unroll
    for (int bb = 0; bb < 4; ++bb)
#pragma unroll
      for (int q = 0; q < 4; ++q) cur[bb][q] = pre[bb][q];
  }

  if (lane < kNT) {
    const size_t s = (size_t)kFP * kNT;
#pragma unroll
    for (int bb = 0; bb < 4; ++bb) {
      const int b = wq * 4 + bb;
      float* ob = out + (((size_t)b * kO + g * kN) * kFP + fi) * (size_t)kNT + lane;
#pragma unroll
      for (int n = 0; n < kN; ++n) ob[(size_t)n * s] = acc[bb][n];
    }
  }
}

extern "C" void kernel_launch(void* const* d_in, const int* in_sizes, int n_in,
                              void* d_out, int out_size, void* d_ws, size_t ws_size,
                              hipStream_t stream) {
  const float* x  = (const float*)d_in[0];
  const float* wt = (const float*)d_in[1];
  float* out      = (float*)d_out;

  dim3 grid(kFP, kG, 1);   // 64 x 8 = 512 blocks of 256 threads (16 b inside)
  lc2d_kernel<<<grid, 256, 0, stream>>>(x, wt, out);
}